// Round 5
// baseline (370.225 us; speedup 1.0000x reference)
//
#include <hip/hip_runtime.h>
#include <stdint.h>

typedef __bf16 bf16x8 __attribute__((ext_vector_type(8)));
typedef float floatx4 __attribute__((ext_vector_type(4)));
typedef unsigned short u16;

__device__ __forceinline__ float bf2f(u16 u) {
    union { uint32_t i; float f; } v; v.i = ((uint32_t)u) << 16; return v.f;
}
__device__ __forceinline__ u16 f2bf(float f) {
    union { float f; uint32_t i; } v; v.f = f;
    uint32_t r = v.i + 0x7fffu + ((v.i >> 16) & 1u);
    return (u16)(r >> 16);
}

#define TM 128
#define TN 128
#define BK 64
#define LDS_STRIDE 72  // u16; 144 B row stride; <=2-way LDS conflicts (free, m136)

// C = A[M,K] @ Bt[N,K]^T + bias[N] (+ addsrc); A,Bt,addsrc bf16; bias fp32; fp32 accum.
// Output: bf16 to C16 (if non-null) else fp32 to C32.
__global__ __launch_bounds__(256) void gemm_bt_kernel(
    const u16* __restrict__ A, int lda,
    const u16* __restrict__ Bt,
    const float* __restrict__ bias,
    const u16* __restrict__ addsrc, int ldadd,
    u16* __restrict__ C16, float* __restrict__ C32, int ldc,
    int K)
{
    __shared__ __attribute__((aligned(16))) u16 lsA[TM * LDS_STRIDE];
    __shared__ __attribute__((aligned(16))) u16 lsB[TN * LDS_STRIDE];
    const int tid  = threadIdx.x;
    const int wave = tid >> 6;
    const int lane = tid & 63;
    const int quad = lane >> 4;
    const int l16  = lane & 15;
    const int wm = wave >> 1, wn = wave & 1;
    const int row0 = blockIdx.y * TM;
    const int col0 = blockIdx.x * TN;

    floatx4 acc[4][4] = {};

    for (int kt = 0; kt < K; kt += BK) {
#pragma unroll
        for (int cc = 0; cc < 4; ++cc) {
            int f = cc * 256 + tid;
            int r = f >> 3, s = f & 7;
            bf16x8 va = *(const bf16x8*)(A  + (size_t)(row0 + r) * lda + kt + s * 8);
            bf16x8 vb = *(const bf16x8*)(Bt + (size_t)(col0 + r) * K   + kt + s * 8);
            *(bf16x8*)&lsA[r * LDS_STRIDE + s * 8] = va;
            *(bf16x8*)&lsB[r * LDS_STRIDE + s * 8] = vb;
        }
        __syncthreads();
#pragma unroll
        for (int ks = 0; ks < 2; ++ks) {
            const int cidx = ks * 4 + quad;
            bf16x8 af[4], bfr[4];
#pragma unroll
            for (int i = 0; i < 4; ++i) {
                int m = wm * 64 + i * 16 + l16;
                af[i] = *(const bf16x8*)&lsA[m * LDS_STRIDE + cidx * 8];
            }
#pragma unroll
            for (int j = 0; j < 4; ++j) {
                int n = wn * 64 + j * 16 + l16;
                bfr[j] = *(const bf16x8*)&lsB[n * LDS_STRIDE + cidx * 8];
            }
#pragma unroll
            for (int i = 0; i < 4; ++i)
#pragma unroll
                for (int j = 0; j < 4; ++j)
                    acc[i][j] = __builtin_amdgcn_mfma_f32_16x16x32_bf16(af[i], bfr[j], acc[i][j], 0, 0, 0);
        }
        __syncthreads();
    }

    // epilogue: C/D layout col=lane&15, row=quad*4+reg  (validated vs VALU GEMM in R3/R4)
#pragma unroll
    for (int j = 0; j < 4; ++j) {
        int col = col0 + wn * 64 + j * 16 + l16;
        float bv = bias[col];
#pragma unroll
        for (int i = 0; i < 4; ++i) {
            int rowb = row0 + wm * 64 + i * 16 + quad * 4;
#pragma unroll
            for (int t = 0; t < 4; ++t) {
                float v = acc[i][j][t] + bv;
                if (addsrc) v += bf2f(addsrc[(size_t)(rowb + t) * ldadd + col]);
                if (C16) C16[(size_t)(rowb + t) * ldc + col] = f2bf(v);
                else     C32[(size_t)(rowb + t) * ldc + col] = v;
            }
        }
    }
}

// Per row of QK[M,1024]: l2-normalize cols 0..511 (Q) and 512..1023 (K) separately,
// write back, accumulate g[b,:] += Qn row. 32 rows per block, 256 threads.
__global__ __launch_bounds__(256) void norm_g_kernel(u16* __restrict__ QK, float* __restrict__ g)
{
    __shared__ float wsum[2][4];
    const int tid = threadIdx.x;
    const int wave = tid >> 6, lane = tid & 63;
    const int row_base = blockIdx.x * 32;
    const int batch = row_base >> 12; // 4096 rows per batch
    float gl0 = 0.f, gl1 = 0.f, gl2 = 0.f, gl3 = 0.f;
    for (int rr = 0; rr < 32; ++rr) {
        const size_t base = (size_t)(row_base + rr) * 1024 + tid * 4;
        ushort4 u = *(const ushort4*)(QK + base);
        float v0 = bf2f(u.x), v1 = bf2f(u.y), v2 = bf2f(u.z), v3 = bf2f(u.w);
        float ss = v0 * v0 + v1 * v1 + v2 * v2 + v3 * v3;
#pragma unroll
        for (int off = 32; off > 0; off >>= 1) ss += __shfl_xor(ss, off);
        if (lane == 0) wsum[rr & 1][wave] = ss;
        __syncthreads();
        float s2 = (wave < 2) ? (wsum[rr & 1][0] + wsum[rr & 1][1])
                              : (wsum[rr & 1][2] + wsum[rr & 1][3]);
        float rs = rsqrtf(fmaxf(s2, 1e-12f));
        v0 *= rs; v1 *= rs; v2 *= rs; v3 *= rs;
        ushort4 o;
        o.x = f2bf(v0); o.y = f2bf(v1); o.z = f2bf(v2); o.w = f2bf(v3);
        *(ushort4*)(QK + base) = o;
        if (wave < 2) { gl0 += v0; gl1 += v1; gl2 += v2; gl3 += v3; }
    }
    if (wave < 2) {
        int d = batch * 512 + tid * 4;
        atomicAdd(&g[d + 0], gl0);
        atomicAdd(&g[d + 1], gl1);
        atomicAdd(&g[d + 2], gl2);
        atomicAdd(&g[d + 3], gl3);
    }
}

// Kn *= g[b] (in place, K half of QK)
__global__ __launch_bounds__(256) void scale_k_kernel(u16* __restrict__ QK, const float* __restrict__ g)
{
    size_t idx = ((size_t)blockIdx.x * 256 + threadIdx.x) * 4; // over M*512
    int row = (int)(idx >> 9);
    int d = (int)(idx & 511);
    int batch = row >> 12;
    u16* p = QK + (size_t)row * 1024 + 512 + d;
    ushort4 u = *(const ushort4*)p;
    float4 gv = *(const float4*)(g + batch * 512 + d);
    ushort4 o;
    o.x = f2bf(bf2f(u.x) * gv.x);
    o.y = f2bf(bf2f(u.y) * gv.y);
    o.z = f2bf(bf2f(u.z) * gv.z);
    o.w = f2bf(bf2f(u.w) * gv.w);
    *(ushort4*)p = o;
}

// x (fp32) -> bf16
__global__ __launch_bounds__(256) void convert_x_kernel(const float* __restrict__ x, u16* __restrict__ xb)
{
    size_t i = ((size_t)blockIdx.x * 256 + threadIdx.x) * 4;
    float4 v = *(const float4*)(x + i);
    ushort4 o;
    o.x = f2bf(v.x); o.y = f2bf(v.y); o.z = f2bf(v.z); o.w = f2bf(v.w);
    *(ushort4*)(xb + i) = o;
}

// Bt[n*512+k] = bf16(W[k*512+n])  (512x512, W fp32)
__global__ __launch_bounds__(256) void transpose_kernel(const float* __restrict__ W, u16* __restrict__ Bt)
{
    int id = blockIdx.x * 256 + threadIdx.x;
    int n = id >> 9, k = id & 511;
    Bt[id] = f2bf(W[(size_t)k * 512 + n]);
}

__global__ __launch_bounds__(256) void bias_cat_kernel(const float* __restrict__ bq, const float* __restrict__ bk,
                                                       float* __restrict__ b)
{
    int id = blockIdx.x * 256 + threadIdx.x; // 0..1023
    b[id] = (id < 512) ? bq[id] : bk[id - 512];
}

extern "C" void kernel_launch(void* const* d_in, const int* in_sizes, int n_in,
                              void* d_out, int out_size, void* d_ws, size_t ws_size,
                              hipStream_t stream)
{
    const float* x  = (const float*)d_in[0];
    const float* wq = (const float*)d_in[1];
    const float* bq = (const float*)d_in[2];
    const float* wk = (const float*)d_in[3];
    const float* bk = (const float*)d_in[4];
    const float* wp = (const float*)d_in[5];
    const float* bp = (const float*)d_in[6];
    const float* wf = (const float*)d_in[7];
    const float* bf = (const float*)d_in[8];
    // d_in[9] = w_g unused: softmax over a size-1 axis is identically 1.

    char* ws = (char*)d_ws;
    // xb aliased with T: xb dead after GEMM1, T born at GEMM2.
    u16*   xb     = (u16*)(ws);                 // 32768 x 512 bf16 = 32 MiB
    u16*   T      = (u16*)(ws);                 // 32768 x 512 bf16 (alias)
    u16*   QK     = (u16*)(ws + 33554432);      // 32768 x 1024 bf16 = 64 MiB
    u16*   Bt1    = (u16*)(ws + 100663296);     // 1024 x 512 bf16 = 1 MiB
    u16*   BtP    = (u16*)(ws + 101711872);     // 512 x 512
    u16*   BtF    = (u16*)(ws + 102236160);     // 512 x 512
    float* biasQK = (float*)(ws + 102760448);   // 1024 fp32
    float* g      = (float*)(ws + 102764544);   // 8 x 512 fp32

    hipMemsetAsync(g, 0, 8 * 512 * sizeof(float), stream);
    convert_x_kernel<<<16384, 256, 0, stream>>>(x, xb);
    bias_cat_kernel<<<4, 256, 0, stream>>>(bq, bk, biasQK);
    transpose_kernel<<<1024, 256, 0, stream>>>(wq, Bt1);
    transpose_kernel<<<1024, 256, 0, stream>>>(wk, Bt1 + 512 * 512);
    transpose_kernel<<<1024, 256, 0, stream>>>(wp, BtP);
    transpose_kernel<<<1024, 256, 0, stream>>>(wf, BtF);

    // QK = x @ [wq|wk] + [bq|bk]          (bf16 out)
    gemm_bt_kernel<<<dim3(8, 256), 256, 0, stream>>>(xb, 512, Bt1, biasQK, nullptr, 0, QK, nullptr, 1024, 512);
    // normalize rows of Q,K halves; g[b] = sum_n Qn
    norm_g_kernel<<<1024, 256, 0, stream>>>(QK, g);
    // Kg = Kn * g[b]
    scale_k_kernel<<<16384, 256, 0, stream>>>(QK, g);
    // T = Kg @ wp + bp + Qn               (bf16 out)
    gemm_bt_kernel<<<dim3(4, 256), 256, 0, stream>>>(QK + 512, 1024, BtP, bp, QK, 1024, T, nullptr, 512, 512);
    // out = T @ wf + bf                   (fp32 out -> d_out)
    gemm_bt_kernel<<<dim3(4, 256), 256, 0, stream>>>(T, 512, BtF, bf, nullptr, 0, nullptr, (float*)d_out, 512, 512);
}